// Round 1
// baseline (188.516 us; speedup 1.0000x reference)
//
#include <hip/hip_runtime.h>
#include <hip/hip_bf16.h>

// GAT: B=4, N=2048, F_IN=F_OUT=256, H=4
#define H 4
#define BB 4
#define NN 2048
#define FIN 256
#define FOUT 256
#define M_TOT (BB*NN)   // 8192
#define LEAKY 0.2f

typedef float f32x4 __attribute__((ext_vector_type(4)));
typedef short s16x8 __attribute__((ext_vector_type(8)));

static __device__ __forceinline__ short f2bf(float f) {
    return __builtin_bit_cast(short, __float2bfloat16(f));
}

// ---------------- prep: X -> bf16 ----------------
__global__ __launch_bounds__(256) void k_convert_x(const float* __restrict__ X, short* __restrict__ Xbf) {
    int idx = blockIdx.x * 1024 + threadIdx.x * 4;
    float4 v = *(const float4*)(X + idx);
    short4 o;
    o.x = f2bf(v.x); o.y = f2bf(v.y); o.z = f2bf(v.z); o.w = f2bf(v.w);
    *(short4*)(Xbf + idx) = o;
}

// ---------------- prep: W[h][k][o] -> WT[h][o][k] (bf16) ----------------
__global__ __launch_bounds__(256) void k_wt(const float* __restrict__ W, short* __restrict__ WT) {
    __shared__ float lds[64][65];
    int bid = blockIdx.x;
    int h = bid >> 4, kt = (bid >> 2) & 3, ot = bid & 3;
    int kb = kt * 64, ob = ot * 64;
    int tx = threadIdx.x & 63, ty = threadIdx.x >> 6;
#pragma unroll
    for (int r = 0; r < 16; ++r) {
        int k_l = ty + r * 4;
        lds[tx][k_l] = W[(size_t)(h * FIN + kb + k_l) * FOUT + ob + tx];
    }
    __syncthreads();
#pragma unroll
    for (int r = 0; r < 16; ++r) {
        int o_l = ty + r * 4;
        WT[(size_t)(h * FOUT + ob + o_l) * FIN + kb + tx] = f2bf(lds[o_l][tx]);
    }
}

// ---------------- prep: q[h][f] = sum_o W[h][f][o]*a[h][o] ----------------
__global__ __launch_bounds__(256) void k_q(const float* __restrict__ W, const float* __restrict__ a,
                                           float* __restrict__ q) {
    int wv = (blockIdx.x * 256 + threadIdx.x) >> 6;  // 0..1023
    int lane = threadIdx.x & 63;
    int h = wv >> 8, f = wv & 255;
    float4 w4 = *(const float4*)(W + (size_t)(h * FIN + f) * FOUT + lane * 4);
    float4 a4 = *(const float4*)(a + h * FOUT + lane * 4);
    float d = w4.x * a4.x + w4.y * a4.y + w4.z * a4.z + w4.w * a4.w;
#pragma unroll
    for (int off = 32; off; off >>= 1) d += __shfl_xor(d, off);
    if (lane == 0) q[h * FIN + f] = d;
}

// ---------------- prep: c[h] = b[h] . a[h] ----------------
__global__ __launch_bounds__(256) void k_c(const float* __restrict__ bvec, const float* __restrict__ a,
                                           float* __restrict__ c) {
    int h = threadIdx.x >> 6, lane = threadIdx.x & 63;
    float4 b4 = *(const float4*)(bvec + h * FOUT + lane * 4);
    float4 a4 = *(const float4*)(a + h * FOUT + lane * 4);
    float d = b4.x * a4.x + b4.y * a4.y + b4.z * a4.z + b4.w * a4.w;
#pragma unroll
    for (int off = 32; off; off >>= 1) d += __shfl_xor(d, off);
    if (lane == 0) c[h] = d;
}

// ---------------- scores: s[h][m] = X[m]·q[h] + c[h]  (exact fp32) ----------------
__global__ __launch_bounds__(256) void k_s(const float* __restrict__ X, const float* __restrict__ q,
                                           const float* __restrict__ c, float* __restrict__ s) {
    int m = blockIdx.x * 4 + (threadIdx.x >> 6);
    int lane = threadIdx.x & 63;
    float4 xv = *(const float4*)(X + (size_t)m * FIN + lane * 4);
#pragma unroll
    for (int h = 0; h < H; ++h) {
        float4 qv = *(const float4*)(q + h * FIN + lane * 4);
        float d = xv.x * qv.x + xv.y * qv.y + xv.z * qv.z + xv.w * qv.w;
#pragma unroll
        for (int off = 32; off; off >>= 1) d += __shfl_xor(d, off);
        if (lane == 0) s[h * M_TOT + m] = d + c[h];
    }
}

// ---------------- tT[h][o][m] = bf16( sum_k W[h][k][o]*X[m][k] + b[h][o] ) ----------------
// D[o][m] = A·B with A = WT rows (contig), B = Xbf rows (contig). No LDS (L2-resident operands).
__global__ __launch_bounds__(256) void k_gemm_t(const short* __restrict__ WT, const short* __restrict__ Xbf,
                                                const float* __restrict__ bvec, short* __restrict__ tT) {
    int h = blockIdx.z;
    int ob = blockIdx.y * 64;
    int mb = blockIdx.x * 128;
    int lane = threadIdx.x & 63, w = threadIdx.x >> 6;
    int r16 = lane & 15, g = lane >> 4;
    int mw = mb + w * 32;
    f32x4 acc[4][2] = {};
    for (int k = 0; k < FIN; k += 32) {
        s16x8 afr[4], bfr[2];
#pragma unroll
        for (int fa = 0; fa < 4; ++fa)
            afr[fa] = *(const s16x8*)(WT + (size_t)(h * FOUT + ob + fa * 16 + r16) * FIN + k + g * 8);
#pragma unroll
        for (int fb = 0; fb < 2; ++fb)
            bfr[fb] = *(const s16x8*)(Xbf + (size_t)(mw + fb * 16 + r16) * FIN + k + g * 8);
#pragma unroll
        for (int fa = 0; fa < 4; ++fa)
#pragma unroll
            for (int fb = 0; fb < 2; ++fb)
                acc[fa][fb] = __builtin_amdgcn_mfma_f32_16x16x32_bf16(afr[fa], bfr[fb], acc[fa][fb], 0, 0, 0);
    }
#pragma unroll
    for (int fa = 0; fa < 4; ++fa) {
#pragma unroll
        for (int r = 0; r < 4; ++r) {
            int o = ob + fa * 16 + g * 4 + r;
            float bv = bvec[h * FOUT + o];
#pragma unroll
            for (int fb = 0; fb < 2; ++fb) {
                int m = mw + fb * 16 + r16;
                tT[(size_t)(h * FOUT + o) * M_TOT + m] = f2bf(acc[fa][fb][r] + bv);
            }
        }
    }
}

// ---------------- flash attention: OT[h][o][m] = (coefs @ t)^T ----------------
// Per block: one (h,b), 64 query rows (4 waves x 16). O^T = tT · P^T; D-col = lane&15 = query row
// => softmax state (m,l) is lane-local, rescale is a scalar multiply.
__global__ __launch_bounds__(256) void k_attn(const short* __restrict__ tT, const float* __restrict__ s,
                                              const float* __restrict__ bias, float* __restrict__ OT) {
    __shared__ short lds_t[256 * 40];  // [o=256][j=32] pad to 40 (2-way bank conflicts only)
    int h = blockIdx.z, b = blockIdx.y;
    int ib = blockIdx.x * 64;
    int tid = threadIdx.x;
    int lane = tid & 63, w = tid >> 6;
    int r16 = lane & 15, g = lane >> 4;
    int i_loc = ib + w * 16 + r16;  // query row within batch b
    size_t gm = (size_t)b * NN;
    float s_i = s[h * M_TOT + gm + i_loc];
    const float* brow = bias + ((size_t)b * NN + i_loc) * NN;
    const float* srow = s + h * M_TOT + gm;
    f32x4 acc[16] = {};
    float mrow = -INFINITY, lrow = 0.f;

    for (int jb = 0; jb < NN; jb += 32) {
        // stage tT tile [256][32] into LDS (each thread: one row, 64B contiguous)
        {
            const short* src = tT + (size_t)(h * FOUT + tid) * M_TOT + gm + jb;
            short* dst = lds_t + tid * 40;
            s16x8 v0 = *(const s16x8*)(src);
            s16x8 v1 = *(const s16x8*)(src + 8);
            s16x8 v2 = *(const s16x8*)(src + 16);
            s16x8 v3 = *(const s16x8*)(src + 24);
            *(s16x8*)(dst) = v0;
            *(s16x8*)(dst + 8) = v1;
            *(s16x8*)(dst + 16) = v2;
            *(s16x8*)(dst + 24) = v3;
        }
        __syncthreads();

        // scores for (row i_loc, j = jb + 8g + e)
        float4 sj0 = *(const float4*)(srow + jb + g * 8);
        float4 sj1 = *(const float4*)(srow + jb + g * 8 + 4);
        float4 bi0 = *(const float4*)(brow + jb + g * 8);
        float4 bi1 = *(const float4*)(brow + jb + g * 8 + 4);
        float sc[8];
        {
            float wv;
            wv = s_i + sj0.x; sc[0] = (wv > 0.f ? wv : LEAKY * wv) + bi0.x;
            wv = s_i + sj0.y; sc[1] = (wv > 0.f ? wv : LEAKY * wv) + bi0.y;
            wv = s_i + sj0.z; sc[2] = (wv > 0.f ? wv : LEAKY * wv) + bi0.z;
            wv = s_i + sj0.w; sc[3] = (wv > 0.f ? wv : LEAKY * wv) + bi0.w;
            wv = s_i + sj1.x; sc[4] = (wv > 0.f ? wv : LEAKY * wv) + bi1.x;
            wv = s_i + sj1.y; sc[5] = (wv > 0.f ? wv : LEAKY * wv) + bi1.y;
            wv = s_i + sj1.z; sc[6] = (wv > 0.f ? wv : LEAKY * wv) + bi1.z;
            wv = s_i + sj1.w; sc[7] = (wv > 0.f ? wv : LEAKY * wv) + bi1.w;
        }
        float tmax = sc[0];
#pragma unroll
        for (int e = 1; e < 8; ++e) tmax = fmaxf(tmax, sc[e]);
        tmax = fmaxf(tmax, __shfl_xor(tmax, 16));
        tmax = fmaxf(tmax, __shfl_xor(tmax, 32));  // full 32-wide row max for this tile

        if (!__all(tmax <= mrow)) {
            float mnew = fmaxf(mrow, tmax);
            float scale = __expf(mrow - mnew);
            lrow *= scale;
#pragma unroll
            for (int f = 0; f < 16; ++f) {
                acc[f][0] *= scale; acc[f][1] *= scale;
                acc[f][2] *= scale; acc[f][3] *= scale;
            }
            mrow = mnew;
        }

        float ps = 0.f;
        s16x8 pb;
#pragma unroll
        for (int e = 0; e < 8; ++e) {
            float p = __expf(sc[e] - mrow);  // exponent <= 0 by construction: no overflow
            ps += p;
            pb[e] = f2bf(p);
        }
        ps += __shfl_xor(ps, 16);
        ps += __shfl_xor(ps, 32);
        lrow += ps;

#pragma unroll
        for (int f = 0; f < 16; ++f) {
            s16x8 af = *(const s16x8*)(lds_t + (f * 16 + r16) * 40 + g * 8);
            acc[f] = __builtin_amdgcn_mfma_f32_16x16x32_bf16(af, pb, acc[f], 0, 0, 0);
        }
        __syncthreads();
    }

    float inv = 1.f / lrow;
#pragma unroll
    for (int f = 0; f < 16; ++f)
#pragma unroll
        for (int r = 0; r < 4; ++r) {
            int o = f * 16 + g * 4 + r;
            OT[(size_t)(h * FOUT + o) * M_TOT + gm + i_loc] = acc[f][r] * inv;
        }
}

// ---------------- head mean + transpose: out[m][o] = 0.25 * sum_h OT[h][o][m] ----------------
__global__ __launch_bounds__(256) void k_reduce(const float* __restrict__ OT, float* __restrict__ out) {
    __shared__ float lds[32][72];
    int mb = blockIdx.x * 64, obt = blockIdx.y * 32;
    int tid = threadIdx.x;
    {
        int o_l = tid >> 3;        // 0..31
        int m_l = (tid & 7) * 8;   // 0..56
        float acc[8] = {};
#pragma unroll
        for (int h = 0; h < H; ++h) {
            const float* p = OT + (size_t)(h * FOUT + obt + o_l) * M_TOT + mb + m_l;
            float4 a0 = *(const float4*)p;
            float4 a1 = *(const float4*)(p + 4);
            acc[0] += a0.x; acc[1] += a0.y; acc[2] += a0.z; acc[3] += a0.w;
            acc[4] += a1.x; acc[5] += a1.y; acc[6] += a1.z; acc[7] += a1.w;
        }
#pragma unroll
        for (int e = 0; e < 8; ++e) lds[o_l][m_l + e] = acc[e] * 0.25f;
    }
    __syncthreads();
    {
        int m_l = tid >> 2;        // 0..63
        int o_l = (tid & 3) * 8;   // 0,8,16,24
        float4 v0, v1;
        v0.x = lds[o_l + 0][m_l]; v0.y = lds[o_l + 1][m_l];
        v0.z = lds[o_l + 2][m_l]; v0.w = lds[o_l + 3][m_l];
        v1.x = lds[o_l + 4][m_l]; v1.y = lds[o_l + 5][m_l];
        v1.z = lds[o_l + 6][m_l]; v1.w = lds[o_l + 7][m_l];
        float* dst = out + (size_t)(mb + m_l) * FOUT + obt + o_l;
        *(float4*)dst = v0;
        *(float4*)(dst + 4) = v1;
    }
}

extern "C" void kernel_launch(void* const* d_in, const int* in_sizes, int n_in,
                              void* d_out, int out_size, void* d_ws, size_t ws_size,
                              hipStream_t stream) {
    const float* X    = (const float*)d_in[0];  // [B,N,FIN]
    const float* bias = (const float*)d_in[1];  // [B,N,N]
    const float* W    = (const float*)d_in[2];  // [H,FIN,FOUT]
    const float* a    = (const float*)d_in[3];  // [H,FOUT]
    const float* bvec = (const float*)d_in[4];  // [H,FOUT]
    float* out = (float*)d_out;                 // [B,N,FOUT] f32

    // workspace layout (needs ~54 MB)
    char* ws = (char*)d_ws;
    short* Xbf = (short*)ws;                              //  4 MB  [8192][256] bf16
    short* WT  = (short*)(ws + (4u << 20));               // 512 KB [H][256][256] bf16
    float* q   = (float*)(ws + (4u << 20) + (768u << 10));//  4 KB
    float* c   = q + H * FIN;                             // 16 B
    float* s   = (float*)(ws + (5u << 20));               // 128 KB [H][8192]
    short* tT  = (short*)(ws + (6u << 20));               // 16 MB  [H][256][8192] bf16
    float* OT  = (float*)(ws + (22u << 20));              // 32 MB  [H][256][8192] f32

    k_convert_x<<<2048, 256, 0, stream>>>(X, Xbf);
    k_wt<<<64, 256, 0, stream>>>(W, WT);
    k_q<<<256, 256, 0, stream>>>(W, a, q);
    k_c<<<1, 256, 0, stream>>>(bvec, a, c);
    k_s<<<2048, 256, 0, stream>>>(X, q, c, s);
    k_gemm_t<<<dim3(64, 4, 4), 256, 0, stream>>>(WT, Xbf, bvec, tT);
    k_attn<<<dim3(32, 4, 4), 256, 0, stream>>>(tT, s, bias, OT);
    k_reduce<<<dim3(128, 8), 256, 0, stream>>>(OT, out);
}

// Round 2
// 142.782 us; speedup vs baseline: 1.3203x; 1.3203x over previous
//
#include <hip/hip_runtime.h>
#include <hip/hip_bf16.h>

// GAT: B=4, N=2048, F_IN=F_OUT=256, H=4
#define H 4
#define BB 4
#define NN 2048
#define FIN 256
#define FOUT 256
#define M_TOT (BB*NN)   // 8192
#define LEAKY 0.2f

typedef float f32x4 __attribute__((ext_vector_type(4)));
typedef short s16x8 __attribute__((ext_vector_type(8)));

static __device__ __forceinline__ short f2bf(float f) {
    return __builtin_bit_cast(short, __float2bfloat16(f));
}
static __device__ __forceinline__ float bf2f(short u) {
    unsigned x = ((unsigned)(unsigned short)u) << 16;
    return __builtin_bit_cast(float, x);
}

// ---------------- prep: W[h][k][o] -> WT[h][o][k] (bf16) ----------------
__global__ __launch_bounds__(256) void k_wt(const float* __restrict__ W, short* __restrict__ WT) {
    __shared__ float lds[64][65];
    int bid = blockIdx.x;
    int h = bid >> 4, kt = (bid >> 2) & 3, ot = bid & 3;
    int kb = kt * 64, ob = ot * 64;
    int tx = threadIdx.x & 63, ty = threadIdx.x >> 6;
#pragma unroll
    for (int r = 0; r < 16; ++r) {
        int k_l = ty + r * 4;
        lds[tx][k_l] = W[(size_t)(h * FIN + kb + k_l) * FOUT + ob + tx];
    }
    __syncthreads();
#pragma unroll
    for (int r = 0; r < 16; ++r) {
        int o_l = ty + r * 4;
        WT[(size_t)(h * FOUT + ob + o_l) * FIN + kb + tx] = f2bf(lds[o_l][tx]);
    }
}

// ---------------- prep: q[h][f] = sum_o W[h][f][o]*a[h][o] ----------------
__global__ __launch_bounds__(256) void k_q(const float* __restrict__ W, const float* __restrict__ a,
                                           float* __restrict__ q) {
    int wv = (blockIdx.x * 256 + threadIdx.x) >> 6;  // 0..1023
    int lane = threadIdx.x & 63;
    int h = wv >> 8, f = wv & 255;
    float4 w4 = *(const float4*)(W + (size_t)(h * FIN + f) * FOUT + lane * 4);
    float4 a4 = *(const float4*)(a + h * FOUT + lane * 4);
    float d = w4.x * a4.x + w4.y * a4.y + w4.z * a4.z + w4.w * a4.w;
#pragma unroll
    for (int off = 32; off; off >>= 1) d += __shfl_xor(d, off);
    if (lane == 0) q[h * FIN + f] = d;
}

// ---------------- prep: c[h] = b[h] . a[h] ----------------
__global__ __launch_bounds__(256) void k_c(const float* __restrict__ bvec, const float* __restrict__ a,
                                           float* __restrict__ c) {
    int h = threadIdx.x >> 6, lane = threadIdx.x & 63;
    float4 b4 = *(const float4*)(bvec + h * FOUT + lane * 4);
    float4 a4 = *(const float4*)(a + h * FOUT + lane * 4);
    float d = b4.x * a4.x + b4.y * a4.y + b4.z * a4.z + b4.w * a4.w;
#pragma unroll
    for (int off = 32; off; off >>= 1) d += __shfl_xor(d, off);
    if (lane == 0) c[h] = d;
}

// ---------------- scores (exact fp32) + X->bf16 conversion (fused) ----------------
__global__ __launch_bounds__(256) void k_s(const float* __restrict__ X, const float* __restrict__ q,
                                           const float* __restrict__ c, float* __restrict__ s,
                                           short* __restrict__ Xbf) {
    int m = blockIdx.x * 4 + (threadIdx.x >> 6);
    int lane = threadIdx.x & 63;
    float4 xv = *(const float4*)(X + (size_t)m * FIN + lane * 4);
    short4 xb;
    xb.x = f2bf(xv.x); xb.y = f2bf(xv.y); xb.z = f2bf(xv.z); xb.w = f2bf(xv.w);
    *(short4*)(Xbf + (size_t)m * FIN + lane * 4) = xb;
#pragma unroll
    for (int h = 0; h < H; ++h) {
        float4 qv = *(const float4*)(q + h * FIN + lane * 4);
        float d = xv.x * qv.x + xv.y * qv.y + xv.z * qv.z + xv.w * qv.w;
#pragma unroll
        for (int off = 32; off; off >>= 1) d += __shfl_xor(d, off);
        if (lane == 0) s[h * M_TOT + m] = d + c[h];
    }
}

// ---------------- bias -> 1-bit edge mask (bias is exactly 0 or -1e9) ----------------
__global__ __launch_bounds__(256) void k_mask(const float* __restrict__ bias, unsigned* __restrict__ mask) {
    size_t t = (size_t)blockIdx.x * 256 + threadIdx.x;  // 0..524287
    const float* p = bias + t * 32;
    unsigned bits = 0;
#pragma unroll
    for (int k = 0; k < 8; ++k) {
        float4 v = *(const float4*)(p + k * 4);
        bits |= (v.x > -1.f ? 1u : 0u) << (k * 4 + 0);
        bits |= (v.y > -1.f ? 1u : 0u) << (k * 4 + 1);
        bits |= (v.z > -1.f ? 1u : 0u) << (k * 4 + 2);
        bits |= (v.w > -1.f ? 1u : 0u) << (k * 4 + 3);
    }
    mask[t] = bits;
}

// ---------------- tT[h][o][m] = bf16( sum_k W[h][k][o]*X[m][k] + b[h][o] ) ----------------
__global__ __launch_bounds__(256) void k_gemm_t(const short* __restrict__ WT, const short* __restrict__ Xbf,
                                                const float* __restrict__ bvec, short* __restrict__ tT) {
    int h = blockIdx.z;
    int ob = blockIdx.y * 64;
    int mb = blockIdx.x * 128;
    int lane = threadIdx.x & 63, w = threadIdx.x >> 6;
    int r16 = lane & 15, g = lane >> 4;
    int mw = mb + w * 32;
    f32x4 acc[4][2] = {};
    for (int k = 0; k < FIN; k += 32) {
        s16x8 afr[4], bfr[2];
#pragma unroll
        for (int fa = 0; fa < 4; ++fa)
            afr[fa] = *(const s16x8*)(WT + (size_t)(h * FOUT + ob + fa * 16 + r16) * FIN + k + g * 8);
#pragma unroll
        for (int fb = 0; fb < 2; ++fb)
            bfr[fb] = *(const s16x8*)(Xbf + (size_t)(mw + fb * 16 + r16) * FIN + k + g * 8);
#pragma unroll
        for (int fa = 0; fa < 4; ++fa)
#pragma unroll
            for (int fb = 0; fb < 2; ++fb)
                acc[fa][fb] = __builtin_amdgcn_mfma_f32_16x16x32_bf16(afr[fa], bfr[fb], acc[fa][fb], 0, 0, 0);
    }
#pragma unroll
    for (int fa = 0; fa < 4; ++fa) {
#pragma unroll
        for (int r = 0; r < 4; ++r) {
            int o = ob + fa * 16 + g * 4 + r;
            float bv = bvec[h * FOUT + o];
#pragma unroll
            for (int fb = 0; fb < 2; ++fb) {
                int m = mw + fb * 16 + r16;
                tT[(size_t)(h * FOUT + o) * M_TOT + m] = f2bf(acc[fa][fb][r] + bv);
            }
        }
    }
}

// ---------------- flash attention: OT[h][o][m] (bf16) ----------------
// 512 threads = 8 waves. Wave w: queries q16=(w>>1)*16.., J-parity par=w&1.
// Each wave-pair LSE-merges at the end. Edge mask replaces bias reads.
// LDS tile [256 o][64 j] bf16, 16B-chunk XOR swizzle (T2). T14 async staging.
__global__ __launch_bounds__(512, 4) void k_attn(const short* __restrict__ tT, const float* __restrict__ s,
                                                 const unsigned* __restrict__ mask, short* __restrict__ OT) {
    __shared__ short lds_t[256 * 64];      // 32KB tile; reused as f32x4 stage in epilogue
    __shared__ float lds_ml[4][64][2];     // 2KB (m,l) exchange

    // T1: bijective XCD swizzle (nwg=512, 512%8==0) -> blocks sharing (h,b) on one XCD
    int flat = blockIdx.x + 32 * (blockIdx.y + 4 * blockIdx.z);
    int swz = (flat & 7) * 64 + (flat >> 3);
    int qt = swz & 31, b = (swz >> 5) & 3, h = swz >> 7;
    int ib = qt * 64;

    int tid = threadIdx.x;
    int lane = tid & 63, w = tid >> 6;
    int r16 = lane & 15, g = lane >> 4;
    int q16 = w >> 1, par = w & 1;
    int i_loc = ib + q16 * 16 + r16;
    size_t gm = (size_t)b * NN;

    float s_i = s[h * M_TOT + gm + i_loc];
    const float* srow = s + h * M_TOT + gm;
    const unsigned* mrowp = mask + ((size_t)(gm + i_loc)) * (NN / 32);

    // staging: thread stages tile row o_st = tid>>1, half hf = tid&1 (32 shorts = 64B)
    int o_st = tid >> 1, hf = tid & 1;
    const short* src = tT + ((size_t)(h * FOUT) + o_st) * M_TOT + gm + hf * 32;
    // LDS read offset (shorts): row r16 (per f: +f*16 rows), chunk (par*4+g) ^ (row&7)
    int rd_base = r16 * 64 + ((((par << 2) + g) ^ (r16 & 7)) << 3);

    f32x4 acc[16] = {};
    float mrow = -1e9f, lrow = 0.f;

    // prologue: issue loads for tile 0
    s16x8 rv0 = *(const s16x8*)(src);
    s16x8 rv1 = *(const s16x8*)(src + 8);
    s16x8 rv2 = *(const s16x8*)(src + 16);
    s16x8 rv3 = *(const s16x8*)(src + 24);

    for (int it = 0; it < 32; ++it) {
        // write staged tile (swizzled)
        int wb = o_st * 64;
        int sw = (o_st & 7);
        *(s16x8*)(lds_t + wb + ((((hf << 2) + 0) ^ sw) << 3)) = rv0;
        *(s16x8*)(lds_t + wb + ((((hf << 2) + 1) ^ sw) << 3)) = rv1;
        *(s16x8*)(lds_t + wb + ((((hf << 2) + 2) ^ sw) << 3)) = rv2;
        *(s16x8*)(lds_t + wb + ((((hf << 2) + 3) ^ sw) << 3)) = rv3;
        __syncthreads();

        // T14: issue next tile's global loads now; they land during compute
        if (it + 1 < 32) {
            const short* nsrc = src + (it + 1) * 64;
            rv0 = *(const s16x8*)(nsrc);
            rv1 = *(const s16x8*)(nsrc + 8);
            rv2 = *(const s16x8*)(nsrc + 16);
            rv3 = *(const s16x8*)(nsrc + 24);
        }

        // scores for this wave's 32-wide window
        int jw = it * 64 + par * 32;
        unsigned mw = mrowp[jw >> 5];
        float4 sj0 = *(const float4*)(srow + jw + g * 8);
        float4 sj1 = *(const float4*)(srow + jw + g * 8 + 4);
        float sjv[8] = {sj0.x, sj0.y, sj0.z, sj0.w, sj1.x, sj1.y, sj1.z, sj1.w};
        float sc[8];
#pragma unroll
        for (int e = 0; e < 8; ++e) {
            float wv = s_i + sjv[e];
            float lv = wv > 0.f ? wv : LEAKY * wv;
            sc[e] = ((mw >> (g * 8 + e)) & 1u) ? lv : -1e9f;
        }
        float tmax = sc[0];
#pragma unroll
        for (int e = 1; e < 8; ++e) tmax = fmaxf(tmax, sc[e]);
        tmax = fmaxf(tmax, __shfl_xor(tmax, 16));
        tmax = fmaxf(tmax, __shfl_xor(tmax, 32));

        // T13: defer-max with THR=8 (p bounded by e^8, fine in f32/bf16)
        if (!__all(tmax <= mrow + 8.f)) {
            float mnew = fmaxf(mrow, tmax);
            float scale = __expf(mrow - mnew);
            lrow *= scale;
#pragma unroll
            for (int f = 0; f < 16; ++f) {
                acc[f][0] *= scale; acc[f][1] *= scale;
                acc[f][2] *= scale; acc[f][3] *= scale;
            }
            mrow = mnew;
        }

        float ps = 0.f;
        s16x8 pb;
#pragma unroll
        for (int e = 0; e < 8; ++e) {
            float p = ((mw >> (g * 8 + e)) & 1u) ? __expf(sc[e] - mrow) : 0.f;
            ps += p;
            pb[e] = f2bf(p);
        }
        ps += __shfl_xor(ps, 16);
        ps += __shfl_xor(ps, 32);
        lrow += ps;

#pragma unroll
        for (int f = 0; f < 16; ++f) {
            s16x8 af = *(const s16x8*)(lds_t + f * 1024 + rd_base);
            acc[f] = __builtin_amdgcn_mfma_f32_16x16x32_bf16(af, pb, acc[f], 0, 0, 0);
        }
        __syncthreads();
    }

    // ---- epilogue: LSE-merge wave pairs (par 1 -> par 0), store bf16 O^T ----
    if (par) {
        lds_ml[q16][lane][0] = mrow;
        lds_ml[q16][lane][1] = lrow;
    }
    __syncthreads();
    float f0 = 0.f, f1 = 0.f;
    if (!par) {
        float m1 = lds_ml[q16][lane][0];
        float l1 = lds_ml[q16][lane][1];
        float ms = fmaxf(mrow, m1);
        float s0 = __expf(mrow - ms);
        float s1 = __expf(m1 - ms);
        float ln = lrow * s0 + l1 * s1;
        float inv = 1.f / ln;
        f0 = s0 * inv; f1 = s1 * inv;
    }
    f32x4* accst = (f32x4*)lds_t;  // [4][8][64] f32x4 = 32KB
#pragma unroll
    for (int r = 0; r < 2; ++r) {
        if (par) {
#pragma unroll
            for (int f = 0; f < 8; ++f) accst[(q16 * 8 + f) * 64 + lane] = acc[r * 8 + f];
        }
        __syncthreads();
        if (!par) {
#pragma unroll
            for (int f = 0; f < 8; ++f) {
                f32x4 v1 = accst[(q16 * 8 + f) * 64 + lane];
                f32x4 v = acc[r * 8 + f] * f0 + v1 * f1;
                int fg = r * 8 + f;
#pragma unroll
                for (int rr = 0; rr < 4; ++rr) {
                    int o = fg * 16 + g * 4 + rr;
                    OT[(size_t)(h * FOUT + o) * M_TOT + gm + i_loc] = f2bf(v[rr]);
                }
            }
        }
        __syncthreads();
    }
}

// ---------------- head mean + transpose: out[m][o] = 0.25 * sum_h OT[h][o][m] ----------------
__global__ __launch_bounds__(256) void k_reduce(const short* __restrict__ OT, float* __restrict__ out) {
    __shared__ float lds[32][72];
    int mb = blockIdx.x * 64, obt = blockIdx.y * 32;
    int tid = threadIdx.x;
    {
        int o_l = tid >> 3;        // 0..31
        int m_l = (tid & 7) * 8;   // 0..56
        float acc[8] = {};
#pragma unroll
        for (int h = 0; h < H; ++h) {
            s16x8 v = *(const s16x8*)(OT + (size_t)(h * FOUT + obt + o_l) * M_TOT + mb + m_l);
#pragma unroll
            for (int e = 0; e < 8; ++e) acc[e] += bf2f(v[e]);
        }
#pragma unroll
        for (int e = 0; e < 8; ++e) lds[o_l][m_l + e] = acc[e] * 0.25f;
    }
    __syncthreads();
    {
        int m_l = tid >> 2;        // 0..63
        int o_l = (tid & 3) * 8;   // 0,8,16,24
        float4 v0, v1;
        v0.x = lds[o_l + 0][m_l]; v0.y = lds[o_l + 1][m_l];
        v0.z = lds[o_l + 2][m_l]; v0.w = lds[o_l + 3][m_l];
        v1.x = lds[o_l + 4][m_l]; v1.y = lds[o_l + 5][m_l];
        v1.z = lds[o_l + 6][m_l]; v1.w = lds[o_l + 7][m_l];
        float* dst = out + (size_t)(mb + m_l) * FOUT + obt + o_l;
        *(float4*)dst = v0;
        *(float4*)(dst + 4) = v1;
    }
}

extern "C" void kernel_launch(void* const* d_in, const int* in_sizes, int n_in,
                              void* d_out, int out_size, void* d_ws, size_t ws_size,
                              hipStream_t stream) {
    const float* X    = (const float*)d_in[0];  // [B,N,FIN]
    const float* bias = (const float*)d_in[1];  // [B,N,N]
    const float* W    = (const float*)d_in[2];  // [H,FIN,FOUT]
    const float* a    = (const float*)d_in[3];  // [H,FOUT]
    const float* bvec = (const float*)d_in[4];  // [H,FOUT]
    float* out = (float*)d_out;                 // [B,N,FOUT] f32

    // workspace layout (~40 MB)
    char* ws = (char*)d_ws;
    short*    Xbf  = (short*)ws;                               //  4 MB  [8192][256] bf16
    short*    WT   = (short*)(ws + (4u << 20));                // 512 KB [H][256][256] bf16
    float*    q    = (float*)(ws + (4u << 20) + (768u << 10)); //  4 KB
    float*    c    = q + H * FIN;                              // 16 B
    float*    s    = (float*)(ws + (5u << 20));                // 128 KB [H][8192]
    short*    tT   = (short*)(ws + (6u << 20));                // 16 MB  [H][256][8192] bf16
    short*    OT   = (short*)(ws + (22u << 20));               // 16 MB  [H][256][8192] bf16
    unsigned* mask = (unsigned*)(ws + (38u << 20));            //  2 MB  [B][N][N/32] bits

    k_wt<<<64, 256, 0, stream>>>(W, WT);
    k_q<<<256, 256, 0, stream>>>(W, a, q);
    k_c<<<1, 256, 0, stream>>>(bvec, a, c);
    k_s<<<2048, 256, 0, stream>>>(X, q, c, s, Xbf);
    k_mask<<<2048, 256, 0, stream>>>(bias, mask);
    k_gemm_t<<<dim3(64, 4, 4), 256, 0, stream>>>(WT, Xbf, bvec, tT);
    k_attn<<<dim3(32, 4, 4), 512, 0, stream>>>(tT, s, mask, OT);
    k_reduce<<<dim3(128, 8), 256, 0, stream>>>(OT, out);
}

// Round 4
// 139.283 us; speedup vs baseline: 1.3535x; 1.0251x over previous
//
#include <hip/hip_runtime.h>
#include <hip/hip_bf16.h>
#include <stdint.h>

// GAT: B=4, N=2048, F_IN=F_OUT=256, H=4
#define H 4
#define BB 4
#define NN 2048
#define FIN 256
#define FOUT 256
#define M_TOT (BB*NN)   // 8192
#define LEAKY 0.2f

typedef float f32x4 __attribute__((ext_vector_type(4)));
typedef short s16x8 __attribute__((ext_vector_type(8)));
typedef unsigned int u32;

static __device__ __forceinline__ short f2bf(float f) {
    return __builtin_bit_cast(short, __float2bfloat16(f));
}
static __device__ __forceinline__ float bf2f(short u) {
    unsigned x = ((unsigned)(unsigned short)u) << 16;
    return __builtin_bit_cast(float, x);
}
// async global->LDS, 16B per lane (dest = uniform base + lane*16)
// NOTE: C-style casts — static_cast cannot addrspace-cast (round-3 compile fail)
static __device__ __forceinline__ void glds16(const void* g, void* l) {
    __builtin_amdgcn_global_load_lds(
        (const __attribute__((address_space(1))) u32*)(g),
        (__attribute__((address_space(3))) u32*)(l), 16, 0, 0);
}

// tTs element address (shorts): LDS-image layout, 32KB tile per (h,b,jt)
// tile = [o:256][8 chunks of 8 shorts], chunk XOR-swizzled by o&7
static __device__ __forceinline__ size_t tts_addr(int h, int b, int o, int j) {
    return ((size_t)((h * 4 + b) * 32 + (j >> 6))) * 16384
         + o * 64 + ((((j >> 3) & 7) ^ (o & 7)) << 3) + (j & 7);
}

// ---------------- prep: W[h][k][o] -> WT[h][o][k] (bf16) ----------------
__global__ __launch_bounds__(256) void k_wt(const float* __restrict__ W, short* __restrict__ WT) {
    __shared__ float lds[64][65];
    int bid = blockIdx.x;
    int h = bid >> 4, kt = (bid >> 2) & 3, ot = bid & 3;
    int kb = kt * 64, ob = ot * 64;
    int tx = threadIdx.x & 63, ty = threadIdx.x >> 6;
#pragma unroll
    for (int r = 0; r < 16; ++r) {
        int k_l = ty + r * 4;
        lds[tx][k_l] = W[(size_t)(h * FIN + kb + k_l) * FOUT + ob + tx];
    }
    __syncthreads();
#pragma unroll
    for (int r = 0; r < 16; ++r) {
        int o_l = ty + r * 4;
        WT[(size_t)(h * FOUT + ob + o_l) * FIN + kb + tx] = f2bf(lds[o_l][tx]);
    }
}

// ---------------- prep: q[h][f] = sum_o W[h][f][o]*a[h][o] ----------------
__global__ __launch_bounds__(256) void k_q(const float* __restrict__ W, const float* __restrict__ a,
                                           float* __restrict__ q) {
    int wv = (blockIdx.x * 256 + threadIdx.x) >> 6;  // 0..1023
    int lane = threadIdx.x & 63;
    int h = wv >> 8, f = wv & 255;
    float4 w4 = *(const float4*)(W + (size_t)(h * FIN + f) * FOUT + lane * 4);
    float4 a4 = *(const float4*)(a + h * FOUT + lane * 4);
    float d = w4.x * a4.x + w4.y * a4.y + w4.z * a4.z + w4.w * a4.w;
#pragma unroll
    for (int off = 32; off; off >>= 1) d += __shfl_xor(d, off);
    if (lane == 0) q[h * FIN + f] = d;
}

// ---------------- prep: c[h] = b[h] . a[h] ----------------
__global__ __launch_bounds__(256) void k_c(const float* __restrict__ bvec, const float* __restrict__ a,
                                           float* __restrict__ c) {
    int h = threadIdx.x >> 6, lane = threadIdx.x & 63;
    float4 b4 = *(const float4*)(bvec + h * FOUT + lane * 4);
    float4 a4 = *(const float4*)(a + h * FOUT + lane * 4);
    float d = b4.x * a4.x + b4.y * a4.y + b4.z * a4.z + b4.w * a4.w;
#pragma unroll
    for (int off = 32; off; off >>= 1) d += __shfl_xor(d, off);
    if (lane == 0) c[h] = d;
}

// ---------------- scores (exact fp32) + X->bf16 conversion (fused) ----------------
__global__ __launch_bounds__(256) void k_s(const float* __restrict__ X, const float* __restrict__ q,
                                           const float* __restrict__ c, float* __restrict__ s,
                                           short* __restrict__ Xbf) {
    int m = blockIdx.x * 4 + (threadIdx.x >> 6);
    int lane = threadIdx.x & 63;
    float4 xv = *(const float4*)(X + (size_t)m * FIN + lane * 4);
    short4 xb;
    xb.x = f2bf(xv.x); xb.y = f2bf(xv.y); xb.z = f2bf(xv.z); xb.w = f2bf(xv.w);
    *(short4*)(Xbf + (size_t)m * FIN + lane * 4) = xb;
#pragma unroll
    for (int h = 0; h < H; ++h) {
        float4 qv = *(const float4*)(q + h * FIN + lane * 4);
        float d = xv.x * qv.x + xv.y * qv.y + xv.z * qv.z + xv.w * qv.w;
#pragma unroll
        for (int off = 32; off; off >>= 1) d += __shfl_xor(d, off);
        if (lane == 0) s[h * M_TOT + m] = d + c[h];
    }
}

// ---------------- bias -> 1-bit edge mask ----------------
__global__ __launch_bounds__(256) void k_mask(const float* __restrict__ bias, unsigned* __restrict__ mask) {
    size_t t = (size_t)blockIdx.x * 256 + threadIdx.x;  // 0..524287
    const float* p = bias + t * 32;
    unsigned bits = 0;
#pragma unroll
    for (int k = 0; k < 8; ++k) {
        float4 v = *(const float4*)(p + k * 4);
        bits |= (v.x > -1.f ? 1u : 0u) << (k * 4 + 0);
        bits |= (v.y > -1.f ? 1u : 0u) << (k * 4 + 1);
        bits |= (v.z > -1.f ? 1u : 0u) << (k * 4 + 2);
        bits |= (v.w > -1.f ? 1u : 0u) << (k * 4 + 3);
    }
    mask[t] = bits;
}

// ---------------- tTs = bf16(X@W + b), written in LDS-image swizzled layout ----------------
__global__ __launch_bounds__(256) void k_gemm_t(const short* __restrict__ WT, const short* __restrict__ Xbf,
                                                const float* __restrict__ bvec, short* __restrict__ tTs) {
    int h = blockIdx.z;
    int ob = blockIdx.y * 64;
    int mb = blockIdx.x * 128;
    int lane = threadIdx.x & 63, w = threadIdx.x >> 6;
    int r16 = lane & 15, g = lane >> 4;
    int mw = mb + w * 32;
    f32x4 acc[4][2] = {};
    for (int k = 0; k < FIN; k += 32) {
        s16x8 afr[4], bfr[2];
#pragma unroll
        for (int fa = 0; fa < 4; ++fa)
            afr[fa] = *(const s16x8*)(WT + (size_t)(h * FOUT + ob + fa * 16 + r16) * FIN + k + g * 8);
#pragma unroll
        for (int fb = 0; fb < 2; ++fb)
            bfr[fb] = *(const s16x8*)(Xbf + (size_t)(mw + fb * 16 + r16) * FIN + k + g * 8);
#pragma unroll
        for (int fa = 0; fa < 4; ++fa)
#pragma unroll
            for (int fb = 0; fb < 2; ++fb)
                acc[fa][fb] = __builtin_amdgcn_mfma_f32_16x16x32_bf16(afr[fa], bfr[fb], acc[fa][fb], 0, 0, 0);
    }
#pragma unroll
    for (int fa = 0; fa < 4; ++fa) {
#pragma unroll
        for (int r = 0; r < 4; ++r) {
            int o = ob + fa * 16 + g * 4 + r;
            float bv = bvec[h * FOUT + o];
#pragma unroll
            for (int fb = 0; fb < 2; ++fb) {
                int m = mw + fb * 16 + r16;
                int bb = m >> 11, j = m & 2047;
                tTs[tts_addr(h, bb, o, j)] = f2bf(acc[fa][fb][r] + bv);
            }
        }
    }
}

// ---------------- flash attention: OT[h][o][m] (bf16) ----------------
// 256 threads = 4 waves. Wave w: 32 query rows (qg=w>>1), J-parity par=w&1.
// A-fragments from glds-staged LDS tile (pre-swizzled global image).
// Double-buffered, counted vmcnt, raw s_barrier (no full drains).
__global__ __launch_bounds__(256, 2) void k_attn(const short* __restrict__ tTs, const float* __restrict__ s,
                                                 const unsigned* __restrict__ mask, short* __restrict__ OT) {
    __shared__ short buf[2][16384];      // 2 x 32KB tile ([256 o][64 j] image)
    __shared__ float lds_ml[2][64][4];   // per-pair (m0,l0,m1,l1) exchange

    // T1: bijective XCD swizzle (512 blocks, 512%8==0)
    int flat = blockIdx.x + 32 * (blockIdx.y + 4 * blockIdx.z);
    int swz = (flat & 7) * 64 + (flat >> 3);
    int qt = swz & 31, b = (swz >> 5) & 3, h = swz >> 7;
    int ib = qt * 64;

    int tid = threadIdx.x;
    int lane = tid & 63, w = tid >> 6;
    int r16 = lane & 15, g = lane >> 4;
    int qg = w >> 1, par = w & 1;
    int i0 = ib + qg * 32 + r16, i1 = i0 + 16;
    size_t gm = (size_t)b * NN;

    const char* slab = (const char*)(tTs + (size_t)(h * 4 + b) * 32 * 16384);
    float si0 = s[h * M_TOT + gm + i0];
    float si1 = s[h * M_TOT + gm + i1];
    const float* srow = s + h * M_TOT + gm;
    const unsigned* mk0 = mask + (gm + i0) * (NN / 32);
    const unsigned* mk1 = mask + (gm + i1) * (NN / 32);

    // LDS read offset (shorts) within tile for A-fragments
    int rd_base = r16 * 64 + ((((par << 2) + g) ^ (r16 & 7)) << 3);

    f32x4 acc[16][2] = {};
    float m0 = -1e9f, l0 = 0.f, m1 = -1e9f, l1 = 0.f;

    // prologue: stage tile 0 into buf0
    {
        const char* gsrc = slab + w * 8192 + lane * 16;
#pragma unroll
        for (int k = 0; k < 8; ++k)
            glds16(gsrc + k * 1024, &buf[0][w * 4096 + k * 512]);
    }
    asm volatile("s_waitcnt vmcnt(0)" ::: "memory");
    __builtin_amdgcn_s_barrier();
    __builtin_amdgcn_sched_barrier(0);

    for (int t = 0; t < 32; ++t) {
        int cur = t & 1;
        int jw = t * 64 + par * 32;
        // ---- scores for 2 rows x 8 elems (j = jw + g*8 + e) ----
        float4 sj0 = *(const float4*)(srow + jw + g * 8);
        float4 sj1 = *(const float4*)(srow + jw + g * 8 + 4);
        unsigned w0 = mk0[t * 2 + par] >> (g * 8);
        unsigned w1 = mk1[t * 2 + par] >> (g * 8);
        float sj[8] = {sj0.x, sj0.y, sj0.z, sj0.w, sj1.x, sj1.y, sj1.z, sj1.w};
        float sc0[8], sc1[8];
#pragma unroll
        for (int e = 0; e < 8; ++e) {
            float y0 = si0 + sj[e];
            float y1 = si1 + sj[e];
            float ly0 = fmaxf(y0, 0.2f * y0);   // leaky = max(y, 0.2y)
            float ly1 = fmaxf(y1, 0.2f * y1);
            sc0[e] = ((w0 >> e) & 1u) ? ly0 : -1e9f;
            sc1[e] = ((w1 >> e) & 1u) ? ly1 : -1e9f;
        }
        float t0 = fmaxf(fmaxf(fmaxf(sc0[0], sc0[1]), fmaxf(sc0[2], sc0[3])),
                         fmaxf(fmaxf(sc0[4], sc0[5]), fmaxf(sc0[6], sc0[7])));
        float t1 = fmaxf(fmaxf(fmaxf(sc1[0], sc1[1]), fmaxf(sc1[2], sc1[3])),
                         fmaxf(fmaxf(sc1[4], sc1[5]), fmaxf(sc1[6], sc1[7])));
        t0 = fmaxf(t0, __shfl_xor(t0, 16)); t0 = fmaxf(t0, __shfl_xor(t0, 32));
        t1 = fmaxf(t1, __shfl_xor(t1, 16)); t1 = fmaxf(t1, __shfl_xor(t1, 32));

        // T13: defer-max (THR=8)
        if (!__all((t0 <= m0 + 8.f) && (t1 <= m1 + 8.f))) {
            float mn0 = fmaxf(m0, t0), mn1 = fmaxf(m1, t1);
            float s0 = __expf(m0 - mn0), s1 = __expf(m1 - mn1);
            l0 *= s0; l1 *= s1;
#pragma unroll
            for (int f = 0; f < 16; ++f) { acc[f][0] *= s0; acc[f][1] *= s1; }
            m0 = mn0; m1 = mn1;
        }

        float ps0 = 0.f, ps1 = 0.f;
        s16x8 pb0, pb1;
#pragma unroll
        for (int e = 0; e < 8; ++e) {
            float p0 = __expf(sc0[e] - m0);
            float p1 = __expf(sc1[e] - m1);
            ps0 += p0; ps1 += p1;
            pb0[e] = f2bf(p0); pb1[e] = f2bf(p1);
        }
        ps0 += __shfl_xor(ps0, 16); ps0 += __shfl_xor(ps0, 32);
        ps1 += __shfl_xor(ps1, 16); ps1 += __shfl_xor(ps1, 32);
        l0 += ps0; l1 += ps1;

        __builtin_amdgcn_sched_barrier(0);
        // ---- issue next tile's glds (lands during MFMA + next scores) ----
        if (t + 1 < 32) {
            const char* gsrc = slab + (size_t)(t + 1) * 32768 + w * 8192 + lane * 16;
#pragma unroll
            for (int k = 0; k < 8; ++k)
                glds16(gsrc + k * 1024, &buf[cur ^ 1][w * 4096 + k * 512]);
        }
        // tile t drained when <=8 (the just-issued batch) outstanding
        asm volatile("s_waitcnt vmcnt(8)" ::: "memory");
        __builtin_amdgcn_s_barrier();
        __builtin_amdgcn_sched_barrier(0);

        // ---- PV MFMAs: 16 A-frags x 2 query-frags ----
        const short* bp = &buf[cur][0];
        __builtin_amdgcn_s_setprio(1);
#pragma unroll
        for (int f = 0; f < 16; ++f) {
            s16x8 af = *(const s16x8*)(bp + f * 1024 + rd_base);
            acc[f][0] = __builtin_amdgcn_mfma_f32_16x16x32_bf16(af, pb0, acc[f][0], 0, 0, 0);
            acc[f][1] = __builtin_amdgcn_mfma_f32_16x16x32_bf16(af, pb1, acc[f][1], 0, 0, 0);
        }
        __builtin_amdgcn_s_setprio(0);
        __builtin_amdgcn_sched_barrier(0);
        __builtin_amdgcn_s_barrier();   // protect buf[cur^1] before next iter's glds
    }

    // ---- epilogue: LSE-merge parity pairs, store bf16 O^T ----
    if (par) {
        lds_ml[qg][lane][0] = m0; lds_ml[qg][lane][1] = l0;
        lds_ml[qg][lane][2] = m1; lds_ml[qg][lane][3] = l1;
    }
    f32x4* ex = (f32x4*)buf;  // 64KB: [2 pairs][16 f][2 qf][64 lanes]
    if (par) {
#pragma unroll
        for (int f = 0; f < 16; ++f) {
            ex[((qg * 16 + f) * 2 + 0) * 64 + lane] = acc[f][0];
            ex[((qg * 16 + f) * 2 + 1) * 64 + lane] = acc[f][1];
        }
    }
    __syncthreads();
    if (!par) {
        float mo0 = lds_ml[qg][lane][0], lo0 = lds_ml[qg][lane][1];
        float mo1 = lds_ml[qg][lane][2], lo1 = lds_ml[qg][lane][3];
        float ms0 = fmaxf(m0, mo0);
        float a0 = __expf(m0 - ms0), b0 = __expf(mo0 - ms0);
        float inv0 = 1.f / (l0 * a0 + lo0 * b0);
        float w00 = a0 * inv0, w01 = b0 * inv0;
        float ms1 = fmaxf(m1, mo1);
        float a1 = __expf(m1 - ms1), b1 = __expf(mo1 - ms1);
        float inv1 = 1.f / (l1 * a1 + lo1 * b1);
        float w10 = a1 * inv1, w11 = b1 * inv1;
        size_t ob0 = (size_t)h * FOUT * M_TOT + gm;
#pragma unroll
        for (int f = 0; f < 16; ++f) {
            f32x4 v0 = acc[f][0] * w00 + ex[((qg * 16 + f) * 2 + 0) * 64 + lane] * w01;
            f32x4 v1 = acc[f][1] * w10 + ex[((qg * 16 + f) * 2 + 1) * 64 + lane] * w11;
#pragma unroll
            for (int rr = 0; rr < 4; ++rr) {
                int o = f * 16 + g * 4 + rr;
                OT[ob0 + (size_t)o * M_TOT + i0] = f2bf(v0[rr]);
                OT[ob0 + (size_t)o * M_TOT + i1] = f2bf(v1[rr]);
            }
        }
    }
}

// ---------------- head mean + transpose: out[m][o] = 0.25 * sum_h OT[h][o][m] ----------------
__global__ __launch_bounds__(256) void k_reduce(const short* __restrict__ OT, float* __restrict__ out) {
    __shared__ float lds[32][72];
    int mb = blockIdx.x * 64, obt = blockIdx.y * 32;
    int tid = threadIdx.x;
    {
        int o_l = tid >> 3;        // 0..31
        int m_l = (tid & 7) * 8;   // 0..56
        float acc[8] = {};
#pragma unroll
        for (int h = 0; h < H; ++h) {
            s16x8 v = *(const s16x8*)(OT + (size_t)(h * FOUT + obt + o_l) * M_TOT + mb + m_l);
#pragma unroll
            for (int e = 0; e < 8; ++e) acc[e] += bf2f(v[e]);
        }
#pragma unroll
        for (int e = 0; e < 8; ++e) lds[o_l][m_l + e] = acc[e] * 0.25f;
    }
    __syncthreads();
    {
        int m_l = tid >> 2;        // 0..63
        int o_l = (tid & 3) * 8;   // 0,8,16,24
        float4 v0, v1;
        v0.x = lds[o_l + 0][m_l]; v0.y = lds[o_l + 1][m_l];
        v0.z = lds[o_l + 2][m_l]; v0.w = lds[o_l + 3][m_l];
        v1.x = lds[o_l + 4][m_l]; v1.y = lds[o_l + 5][m_l];
        v1.z = lds[o_l + 6][m_l]; v1.w = lds[o_l + 7][m_l];
        float* dst = out + (size_t)(mb + m_l) * FOUT + obt + o_l;
        *(float4*)dst = v0;
        *(float4*)(dst + 4) = v1;
    }
}

extern "C" void kernel_launch(void* const* d_in, const int* in_sizes, int n_in,
                              void* d_out, int out_size, void* d_ws, size_t ws_size,
                              hipStream_t stream) {
    const float* X    = (const float*)d_in[0];  // [B,N,FIN]
    const float* bias = (const float*)d_in[1];  // [B,N,N]
    const float* W    = (const float*)d_in[2];  // [H,FIN,FOUT]
    const float* a    = (const float*)d_in[3];  // [H,FOUT]
    const float* bvec = (const float*)d_in[4];  // [H,FOUT]
    float* out = (float*)d_out;                 // [B,N,FOUT] f32

    // workspace layout (~40 MB)
    char* ws = (char*)d_ws;
    short*    Xbf  = (short*)ws;                               //  4 MB  [8192][256] bf16
    short*    WT   = (short*)(ws + (4u << 20));                // 512 KB [H][256][256] bf16
    float*    q    = (float*)(ws + (4u << 20) + (768u << 10)); //  4 KB
    float*    c    = q + H * FIN;                              // 16 B
    float*    s    = (float*)(ws + (5u << 20));                // 128 KB [H][8192]
    short*    tTs  = (short*)(ws + (6u << 20));                // 16 MB  swizzled tile images
    short*    OT   = (short*)(ws + (22u << 20));               // 16 MB  [H][256][8192] bf16
    unsigned* mask = (unsigned*)(ws + (38u << 20));            //  2 MB  [B][N][N/32] bits

    k_wt<<<64, 256, 0, stream>>>(W, WT);
    k_q<<<256, 256, 0, stream>>>(W, a, q);
    k_c<<<1, 256, 0, stream>>>(bvec, a, c);
    k_s<<<2048, 256, 0, stream>>>(X, q, c, s, Xbf);
    k_mask<<<2048, 256, 0, stream>>>(bias, mask);
    k_gemm_t<<<dim3(64, 4, 4), 256, 0, stream>>>(WT, Xbf, bvec, tTs);
    k_attn<<<dim3(32, 4, 4), 256, 0, stream>>>(tTs, s, mask, OT);
    k_reduce<<<dim3(128, 8), 256, 0, stream>>>(OT, out);
}